// Round 6
// baseline (287.304 us; speedup 1.0000x reference)
//
#include <hip/hip_runtime.h>
#include <math.h>

// B=16, H=12, S=1024, D=64.  BH=192, rows = B*H*S = 196608.
// R6: R4 geometry + R5's linear weight layout = both levers at once.
//   R5 post-mortem: 128-row q-blocks raised occupancy (30%) but halved the
//   compute:proj ratio per barrier interval (4:1 -> 2:1) -> slower (148us).
//   R4 had the right ratio but 2 blocks/CU (LDS 55.3KB) and ragged packing
//   (768 blocks / 512 slots = 1.5 rounds).
//   - 256 q-rows/block, grid 192x4 = 768 blocks (compute:proj 4:1 restored).
//   - Wk/Wv in fragment-major linear LDS lw[2][8][64][8] (16KB, reads at
//     base+lane*16, conflict-free; layout correctness-proven in R5).
//   - LDS = union(xq 36.9K | k/v dbuf 36.9K) + 16K = 52KB -> 3 blocks/CU,
//     768 = 256 CU x 3 = exactly ONE resident round (no tail).
//   - __launch_bounds__(256,3): cap 168 >> R4's measured 108 VGPR, no spill.
//   - 1 barrier per 64-key step (dbuf), prefetch, s_setprio around compute.
//
// KEY-PERMUTATION TRICK (unchanged): P^T exits QK in C-layout; reinterpreted
// as a B-fragment it supplies key kappa(s) at MFMA k-slot s.  Vt and Wo are
// stored/loaded pre-permuted by kappa so P and O feed MFMA from registers.
// kappa: s = 16t + 4q + r  ->  32*(t>>1) + 8*q + 4*(t&1) + r.

typedef __bf16 bf16x8 __attribute__((ext_vector_type(8)));
typedef float  f32x4  __attribute__((ext_vector_type(4)));

#define MFMA(a, b, c) __builtin_amdgcn_mfma_f32_16x16x32_bf16((a), (b), (c), 0, 0, 0)

static constexpr int S = 1024;
static constexpr int PAD = 72;      // 144 B row stride: 16B-aligned, breaks 128B aliasing
// Q prescale: 1/sqrt(64) * log2(e)  -> scores arrive pre-scaled for exp2
static constexpr float QSCALE = 0.125f * 1.4426950408889634f;

__device__ inline unsigned long long pack4bf(float a, float b, float c, float d) {
    union { __bf16 h[4]; unsigned long long u; } pk;
    pk.h[0] = (__bf16)a; pk.h[1] = (__bf16)b; pk.h[2] = (__bf16)c; pk.h[3] = (__bf16)d;
    return pk.u;
}

union frag_u { bf16x8 v; unsigned long long u[2]; };

// ---------------------------------------------------------------------------
__global__ __launch_bounds__(256, 3) void attn(
    const float* __restrict__ x,
    const float* __restrict__ Wq, const float* __restrict__ bq,
    const float* __restrict__ Wk, const float* __restrict__ bk,
    const float* __restrict__ Wv, const float* __restrict__ bv,
    const float* __restrict__ Wo, const float* __restrict__ bo,
    float* __restrict__ out)
{
    __shared__ __align__(16) union {
        __bf16 xq[256][PAD];            // prologue: x (q rows), then Q roundtrip
        struct {
            __bf16 k[2][64][PAD];       // K tile [key][d], double-buffered
            __bf16 v[2][64][PAD];       // Vt tile [d][key-kappa], double-buffered
        } m;
    } L;
    // Wk/Wv in linear fragment-major layout: lw[mtx][et*2+half][lane][8elems].
    // Fragment read = 16B at base+lane*16 (contiguous 1KB) -> conflict-free.
    __shared__ __align__(16) __bf16 lw[2][8][64][8];

    const int tid = threadIdx.x;
    const int w = tid >> 6, lane = tid & 63, m = lane & 15, quad = lane >> 4;
    const int bh = blockIdx.x;
    const int q0 = blockIdx.y * 256 + w * 64;

    // ---- prologue: stage my 256 x-rows fp32->bf16, and Wk/Wv fragments ----
    const float* xq32 = x + ((size_t)bh * 1024 + blockIdx.y * 256) * 64;
    #pragma unroll
    for (int i = tid * 4; i < 16384; i += 1024) {
        float4 v = *(const float4*)(xq32 + i);
        int r = i >> 6, c = i & 63;
        *(unsigned long long*)&L.xq[r][c] = pack4bf(v.x, v.y, v.z, v.w);
    }
    #pragma unroll
    for (int c = tid; c < 1024; c += 256) {
        int mtx = c >> 9, rest = c & 511;
        int fe = rest >> 6, ln = rest & 63;
        int mm = ln & 15, qq = ln >> 4;
        int et = fe >> 1, half = fe & 1;
        const float* src = (mtx ? Wv : Wk) + (size_t)(et * 16 + mm) * 64 + half * 32 + qq * 8;
        float4 u0 = *(const float4*)(src);
        float4 u1 = *(const float4*)(src + 4);
        *(unsigned long long*)&lw[mtx][fe][ln][0] = pack4bf(u0.x, u0.y, u0.z, u0.w);
        *(unsigned long long*)&lw[mtx][fe][ln][4] = pack4bf(u1.x, u1.y, u1.z, u1.w);
    }
    __syncthreads();

    // xqf read, Q-proj write, qf read: all touch only this wave's 64 rows
    // (w*64 .. w*64+63), so no barriers needed until the union is re-purposed.
    bf16x8 xqf[4][2];
    #pragma unroll
    for (int g = 0; g < 4; g++) {
        xqf[g][0] = *(const bf16x8*)&L.xq[w * 64 + g * 16 + m][quad * 8];
        xqf[g][1] = *(const bf16x8*)&L.xq[w * 64 + g * 16 + m][32 + quad * 8];
    }
    #pragma unroll
    for (int et = 0; et < 4; et++) {
        const float* wqrow = Wq + (size_t)(et * 16 + m) * 64;
        float4 a0 = *(const float4*)(wqrow + quad * 8);
        float4 a1 = *(const float4*)(wqrow + quad * 8 + 4);
        float4 a2 = *(const float4*)(wqrow + 32 + quad * 8);
        float4 a3 = *(const float4*)(wqrow + 36 + quad * 8);
        frag_u wf0, wf1;
        wf0.u[0] = pack4bf(a0.x, a0.y, a0.z, a0.w);
        wf0.u[1] = pack4bf(a1.x, a1.y, a1.z, a1.w);
        wf1.u[0] = pack4bf(a2.x, a2.y, a2.z, a2.w);
        wf1.u[1] = pack4bf(a3.x, a3.y, a3.z, a3.w);
        float4 bias = *(const float4*)(bq + et * 16 + quad * 4);
        #pragma unroll
        for (int g = 0; g < 4; g++) {
            f32x4 acc = {0.f, 0.f, 0.f, 0.f};
            acc = MFMA(wf0.v, xqf[g][0], acc);
            acc = MFMA(wf1.v, xqf[g][1], acc);
            *(unsigned long long*)&L.xq[w * 64 + g * 16 + m][et * 16 + quad * 4] =
                pack4bf((acc[0] + bias.x) * QSCALE, (acc[1] + bias.y) * QSCALE,
                        (acc[2] + bias.z) * QSCALE, (acc[3] + bias.w) * QSCALE);
        }
    }
    bf16x8 qf[4][2];
    #pragma unroll
    for (int g = 0; g < 4; g++) {
        qf[g][0] = *(const bf16x8*)&L.xq[w * 64 + g * 16 + m][quad * 8];
        qf[g][1] = *(const bf16x8*)&L.xq[w * 64 + g * 16 + m][32 + quad * 8];
    }
    __syncthreads();    // everyone done with xq; union becomes k/v buffers

    float4 bkr[4];
    float  bvr[4];
    #pragma unroll
    for (int et = 0; et < 4; et++) {
        bkr[et] = *(const float4*)(bk + et * 16 + quad * 4);
        bvr[et] = bv[et * 16 + m];
    }

    f32x4 o[4][4];
    float lsum[4] = {0.f, 0.f, 0.f, 0.f};
    #pragma unroll
    for (int g = 0; g < 4; g++)
        #pragma unroll
        for (int n = 0; n < 4; n++) o[g][n] = {0.f, 0.f, 0.f, 0.f};

    const float* xk32 = x + (size_t)bh * 1024 * 64;          // fp32 keys, this bh
    const int p0 = 32 * (w >> 1) + 8 * quad + 4 * (w & 1);   // kappa base, tile t=w

    // ---- tile 0 projected into buffer 0 ----
    {
        const float* xrow = xk32 + (size_t)(w * 16 + m) * 64;
        float4 a0 = *(const float4*)(xrow + quad * 8);
        float4 a1 = *(const float4*)(xrow + quad * 8 + 4);
        float4 a2 = *(const float4*)(xrow + 32 + quad * 8);
        float4 a3 = *(const float4*)(xrow + 36 + quad * 8);
        frag_u xk0, xk1;
        xk0.u[0] = pack4bf(a0.x, a0.y, a0.z, a0.w);
        xk0.u[1] = pack4bf(a1.x, a1.y, a1.z, a1.w);
        xk1.u[0] = pack4bf(a2.x, a2.y, a2.z, a2.w);
        xk1.u[1] = pack4bf(a3.x, a3.y, a3.z, a3.w);
        #pragma unroll
        for (int et = 0; et < 4; et++) {
            bf16x8 kw0 = *(const bf16x8*)&lw[0][et * 2 + 0][lane][0];
            bf16x8 kw1 = *(const bf16x8*)&lw[0][et * 2 + 1][lane][0];
            f32x4 ka = {0.f, 0.f, 0.f, 0.f};
            ka = MFMA(kw0, xk0.v, ka);
            ka = MFMA(kw1, xk1.v, ka);
            *(unsigned long long*)&L.m.k[0][w * 16 + m][et * 16 + quad * 4] =
                pack4bf(ka[0] + bkr[et].x, ka[1] + bkr[et].y,
                        ka[2] + bkr[et].z, ka[3] + bkr[et].w);
            bf16x8 vw0 = *(const bf16x8*)&lw[1][et * 2 + 0][lane][0];
            bf16x8 vw1 = *(const bf16x8*)&lw[1][et * 2 + 1][lane][0];
            f32x4 va = {0.f, 0.f, 0.f, 0.f};
            va = MFMA(xk0.v, vw0, va);
            va = MFMA(xk1.v, vw1, va);
            *(unsigned long long*)&L.m.v[0][et * 16 + m][p0] =
                pack4bf(va[0] + bvr[et], va[1] + bvr[et],
                        va[2] + bvr[et], va[3] + bvr[et]);
        }
    }

    // ---- main loop: 1 barrier per 64-key step; proj(kb+1) overlaps compute(kb) ----
    for (int kb = 0; kb < 16; kb++) {
        __syncthreads();                 // buf[cur] complete for all waves
        const int cur = kb & 1;

        // issue next tile's x loads early (latency hides under compute)
        float4 a0, a1, a2, a3;
        if (kb < 15) {
            const float* xrow = xk32 + (size_t)((kb + 1) * 64 + w * 16 + m) * 64;
            a0 = *(const float4*)(xrow + quad * 8);
            a1 = *(const float4*)(xrow + quad * 8 + 4);
            a2 = *(const float4*)(xrow + 32 + quad * 8);
            a3 = *(const float4*)(xrow + 36 + quad * 8);
        }

        // ---- compute phase: QK -> exp2 -> PV on buf[cur] ----
        __builtin_amdgcn_s_setprio(1);
        #pragma unroll
        for (int gp = 0; gp < 2; gp++) {
            frag_u pb[2][2];
            #pragma unroll
            for (int t = 0; t < 4; t++) {
                bf16x8 ka0 = *(const bf16x8*)&L.m.k[cur][t * 16 + m][quad * 8];
                bf16x8 ka1 = *(const bf16x8*)&L.m.k[cur][t * 16 + m][32 + quad * 8];
                #pragma unroll
                for (int gl = 0; gl < 2; gl++) {
                    const int g = gp * 2 + gl;
                    f32x4 acc = {0.f, 0.f, 0.f, 0.f};
                    acc = MFMA(ka0, qf[g][0], acc);
                    acc = MFMA(ka1, qf[g][1], acc);
                    float e0 = __builtin_amdgcn_exp2f(acc[0]);
                    float e1 = __builtin_amdgcn_exp2f(acc[1]);
                    float e2 = __builtin_amdgcn_exp2f(acc[2]);
                    float e3 = __builtin_amdgcn_exp2f(acc[3]);
                    lsum[g] += (e0 + e1) + (e2 + e3);
                    pb[gl][t >> 1].u[t & 1] = pack4bf(e0, e1, e2, e3);
                }
            }
            #pragma unroll
            for (int n = 0; n < 4; n++) {
                bf16x8 va0 = *(const bf16x8*)&L.m.v[cur][n * 16 + m][quad * 8];
                bf16x8 va1 = *(const bf16x8*)&L.m.v[cur][n * 16 + m][32 + quad * 8];
                #pragma unroll
                for (int gl = 0; gl < 2; gl++) {
                    const int g = gp * 2 + gl;
                    o[g][n] = MFMA(va0, pb[gl][0].v, o[g][n]);
                    o[g][n] = MFMA(va1, pb[gl][1].v, o[g][n]);
                }
            }
        }
        __builtin_amdgcn_s_setprio(0);

        // ---- proj phase: project tile kb+1 into buf[cur^1] (no barrier) ----
        if (kb < 15) {
            frag_u xk0, xk1;
            xk0.u[0] = pack4bf(a0.x, a0.y, a0.z, a0.w);
            xk0.u[1] = pack4bf(a1.x, a1.y, a1.z, a1.w);
            xk1.u[0] = pack4bf(a2.x, a2.y, a2.z, a2.w);
            xk1.u[1] = pack4bf(a3.x, a3.y, a3.z, a3.w);
            #pragma unroll
            for (int et = 0; et < 4; et++) {
                bf16x8 kw0 = *(const bf16x8*)&lw[0][et * 2 + 0][lane][0];
                bf16x8 kw1 = *(const bf16x8*)&lw[0][et * 2 + 1][lane][0];
                f32x4 ka = {0.f, 0.f, 0.f, 0.f};
                ka = MFMA(kw0, xk0.v, ka);
                ka = MFMA(kw1, xk1.v, ka);
                *(unsigned long long*)&L.m.k[cur ^ 1][w * 16 + m][et * 16 + quad * 4] =
                    pack4bf(ka[0] + bkr[et].x, ka[1] + bkr[et].y,
                            ka[2] + bkr[et].z, ka[3] + bkr[et].w);
                bf16x8 vw0 = *(const bf16x8*)&lw[1][et * 2 + 0][lane][0];
                bf16x8 vw1 = *(const bf16x8*)&lw[1][et * 2 + 1][lane][0];
                f32x4 va = {0.f, 0.f, 0.f, 0.f};
                va = MFMA(xk0.v, vw0, va);
                va = MFMA(xk1.v, vw1, va);
                *(unsigned long long*)&L.m.v[cur ^ 1][et * 16 + m][p0] =
                    pack4bf(va[0] + bvr[et], va[1] + bvr[et],
                            va[2] + bvr[et], va[3] + bvr[et]);
            }
        }
    }

    // ---- epilogue: l reduce, O^T regs -> A-fragments, fused @ Wo + bo ----
    #pragma unroll
    for (int g = 0; g < 4; g++) {
        lsum[g] += __shfl_xor(lsum[g], 16);
        lsum[g] += __shfl_xor(lsum[g], 32);
    }

    // Wo fragments with kappa folded into the load addresses:
    bf16x8 wf[4][2];
    #pragma unroll
    for (int et = 0; et < 4; et++) {
        const float* worow = Wo + (size_t)(et * 16 + m) * 64;
        float4 c0 = *(const float4*)(worow + 4 * quad);
        float4 c1 = *(const float4*)(worow + 16 + 4 * quad);
        float4 c2 = *(const float4*)(worow + 32 + 4 * quad);
        float4 c3 = *(const float4*)(worow + 48 + 4 * quad);
        frag_u f0, f1;
        f0.u[0] = pack4bf(c0.x, c0.y, c0.z, c0.w);
        f0.u[1] = pack4bf(c1.x, c1.y, c1.z, c1.w);
        f1.u[0] = pack4bf(c2.x, c2.y, c2.z, c2.w);
        f1.u[1] = pack4bf(c3.x, c3.y, c3.z, c3.w);
        wf[et][0] = f0.v;
        wf[et][1] = f1.v;
    }
    float biasr[4];
    #pragma unroll
    for (int et = 0; et < 4; et++) biasr[et] = bo[et * 16 + m];

    #pragma unroll
    for (int g = 0; g < 4; g++) {
        const float inv = 1.f / lsum[g];
        frag_u af0, af1;
        af0.u[0] = pack4bf(o[g][0][0] * inv, o[g][0][1] * inv, o[g][0][2] * inv, o[g][0][3] * inv);
        af0.u[1] = pack4bf(o[g][1][0] * inv, o[g][1][1] * inv, o[g][1][2] * inv, o[g][1][3] * inv);
        af1.u[0] = pack4bf(o[g][2][0] * inv, o[g][2][1] * inv, o[g][2][2] * inv, o[g][2][3] * inv);
        af1.u[1] = pack4bf(o[g][3][0] * inv, o[g][3][1] * inv, o[g][3][2] * inv, o[g][3][3] * inv);
        #pragma unroll
        for (int et = 0; et < 4; et++) {
            f32x4 acc = {0.f, 0.f, 0.f, 0.f};
            acc = MFMA(af0.v, wf[et][0], acc);
            acc = MFMA(af1.v, wf[et][1], acc);
            #pragma unroll
            for (int r = 0; r < 4; r++) {
                size_t row = (size_t)bh * S + q0 + g * 16 + quad * 4 + r;
                out[row * 64 + et * 16 + m] = acc[r] + biasr[et];
            }
        }
    }
}

// ---------------------------------------------------------------------------
extern "C" void kernel_launch(void* const* d_in, const int* in_sizes, int n_in,
                              void* d_out, int out_size, void* d_ws, size_t ws_size,
                              hipStream_t stream) {
    const float* x  = (const float*)d_in[0];
    const float* Wq = (const float*)d_in[1];
    const float* bq = (const float*)d_in[2];
    const float* Wk = (const float*)d_in[3];
    const float* bk = (const float*)d_in[4];
    const float* Wv = (const float*)d_in[5];
    const float* bv = (const float*)d_in[6];
    const float* Wo = (const float*)d_in[7];
    const float* bo = (const float*)d_in[8];
    float* out = (float*)d_out;

    attn<<<dim3(192, 4), 256, 0, stream>>>(x, Wq, bq, Wk, bk, Wv, bv, Wo, bo, out);
}

// Round 7
// 195.254 us; speedup vs baseline: 1.4714x; 1.4714x over previous
//
#include <hip/hip_runtime.h>
#include <math.h>

// B=16, H=12, S=1024, D=64.  BH=192, rows = B*H*S = 196608.
// R7: R2 pipeline (prep + fused attn), attn de-fattened.
//   Ledger (R2-R6): wall = kernel-sum + ~78us fixed overhead; best sum = R2's
//   prep(13) + attn(104.5).  R3/R6 proved 256-row geometry spills below a
//   256-reg/wave budget -> 2 waves/SIMD is its ceiling; optimize within it.
//   Changes vs R2 attn (all proven pieces):
//   - key-x fragments read DIRECTLY from xb global (L2-hot, prefetched 1 kb
//     ahead right after barrier A): xk LDS roundtrip + its barrier + its
//     conflicted writes + 4 pack4bf/lane/kb all deleted.  3 -> 2 barriers/kb.
//   - Wk/Wv in fragment-major linear LDS lw[2][8][64][8] (16KB, reads at
//     base+lane*16, conflict-free; R5/R6-proven), staged by uint4 copy.
//   - __launch_bounds__(256,2) (R4-proven no-spill), s_setprio on compute.
// ws layout (bf16): xb[NE] | Wo_perm[4096] | Wq[4096] | Wk[4096] | Wv[4096]
//
// KEY-PERMUTATION TRICK (unchanged): P^T exits QK in C-layout; reinterpreted
// as a B-fragment it supplies key kappa(s) at MFMA k-slot s.  Vt and Wo are
// stored pre-permuted by kappa so P and O feed MFMA straight from registers.
// kappa: s = 16t + 4q + r  ->  32*(t>>1) + 8*q + 4*(t&1) + r.

typedef __bf16 bf16x8 __attribute__((ext_vector_type(8)));
typedef float  f32x4  __attribute__((ext_vector_type(4)));

#define MFMA(a, b, c) __builtin_amdgcn_mfma_f32_16x16x32_bf16((a), (b), (c), 0, 0, 0)

static constexpr int S = 1024;
static constexpr int PAD = 72;      // 144 B row stride: 16B-aligned, breaks 128B aliasing
static constexpr size_t NE = 196608ull * 64ull;
// Q prescale: 1/sqrt(64) * log2(e)  -> scores arrive pre-scaled for exp2
static constexpr float QSCALE = 0.125f * 1.4426950408889634f;

__device__ inline unsigned long long pack4bf(float a, float b, float c, float d) {
    union { __bf16 h[4]; unsigned long long u; } pk;
    pk.h[0] = (__bf16)a; pk.h[1] = (__bf16)b; pk.h[2] = (__bf16)c; pk.h[3] = (__bf16)d;
    return pk.u;
}

union frag_u { bf16x8 v; unsigned long long u[2]; };

// ---------------------------------------------------------------------------
// Kernel 0: prep (verbatim R2).  blocks 0..6143: x fp32 -> bf16.
// blocks 6144..6159: weight conversions (Wq/Wk/Wv plain, Wo kappa-permuted).
// ---------------------------------------------------------------------------
__global__ void prep(const float* __restrict__ x,
                     const float* __restrict__ Wq, const float* __restrict__ Wk,
                     const float* __restrict__ Wv, const float* __restrict__ Wo,
                     __bf16* __restrict__ xb,
                     __bf16* __restrict__ wqb, __bf16* __restrict__ wkb,
                     __bf16* __restrict__ wvb, __bf16* __restrict__ wob)
{
    const int bid = blockIdx.x;
    if (bid < 6144) {
        size_t p = ((size_t)bid * 256 + threadIdx.x) * 8;
        float4 a = *(const float4*)(x + p);
        float4 b = *(const float4*)(x + p + 4);
        union { unsigned long long u64[2]; uint4 v; } pk;
        pk.u64[0] = pack4bf(a.x, a.y, a.z, a.w);
        pk.u64[1] = pack4bf(b.x, b.y, b.z, b.w);
        *(uint4*)(xb + p) = pk.v;
    } else {
        const int wb  = bid - 6144;
        const int grp = wb >> 2;                                // 0..3: q,k,v,o
        const int p   = (((wb & 3) * 256) + threadIdx.x) * 4;   // 0..4092
        if (grp == 3) {
            int e = p >> 6, s = p & 63;
            int h = s >> 5, qp = (s >> 3) & 3, tb = (s >> 2) & 1;
            int d0 = 32 * h + 16 * tb + 4 * qp;                 // kappa(s) for s&3==0
            float4 v = *(const float4*)(Wo + e * 64 + d0);
            *(unsigned long long*)(wob + p) = pack4bf(v.x, v.y, v.z, v.w);
        } else {
            const float* src = (grp == 0) ? Wq : (grp == 1) ? Wk : Wv;
            __bf16*      dst = (grp == 0) ? wqb : (grp == 1) ? wkb : wvb;
            float4 v = *(const float4*)(src + p);
            *(unsigned long long*)(dst + p) = pack4bf(v.x, v.y, v.z, v.w);
        }
    }
}

// ---------------------------------------------------------------------------
// Kernel 1: fused QKV-proj + flash attention + output projection.
// Grid (192 bh, 4 qb) x 256.  2 barriers per 64-key step, single-buffer K/V.
// LDS = union(xq 36.9K | k+v 18.4K) + lw 16K = 53.25 KB.
// ---------------------------------------------------------------------------
__global__ __launch_bounds__(256, 2) void attn(
    const __bf16* __restrict__ xb,
    const __bf16* __restrict__ wqb, const __bf16* __restrict__ wkb,
    const __bf16* __restrict__ wvb, const __bf16* __restrict__ wob,
    const float* __restrict__ bq, const float* __restrict__ bk,
    const float* __restrict__ bv, const float* __restrict__ bo,
    float* __restrict__ out)
{
    __shared__ __align__(16) union {
        __bf16 xq[256][PAD];            // prologue: x (q rows), then Q roundtrip
        struct {
            __bf16 k[64][PAD];          // K tile [key][d]
            __bf16 v[64][PAD];          // Vt tile [d][key-kappa]
        } m;
    } L;
    // Wk/Wv in linear fragment-major layout: lw[mtx][et*2+half][lane][8elems].
    // Fragment read = 16B at base+lane*16 (contiguous 1KB) -> conflict-free.
    __shared__ __align__(16) __bf16 lw[2][8][64][8];

    const int tid = threadIdx.x;
    const int w = tid >> 6, lane = tid & 63, m = lane & 15, quad = lane >> 4;
    const int bh = blockIdx.x;
    const int q0 = blockIdx.y * 256 + w * 64;

    // ---- prologue: stage my 256 x-rows (bf16 copy) + lw fragments ----
    const __bf16* xqbase = xb + ((size_t)bh * 1024 + blockIdx.y * 256) * 64;
    #pragma unroll
    for (int i = tid * 8, it = 0; it < 8; i += 2048, it++) {
        int r = i >> 6, c = i & 63;
        *(uint4*)&L.xq[r][c] = *(const uint4*)(xqbase + i);
    }
    #pragma unroll
    for (int c = tid; c < 1024; c += 256) {
        int mtx = c >> 9, rest = c & 511;
        int fe = rest >> 6, ln = rest & 63;
        int mm = ln & 15, qq = ln >> 4;
        int et = fe >> 1, half = fe & 1;
        const __bf16* src = (mtx ? wvb : wkb) + (size_t)(et * 16 + mm) * 64 + half * 32 + qq * 8;
        *(uint4*)&lw[mtx][fe][ln][0] = *(const uint4*)src;
    }
    __syncthreads();

    // Q-proj: reads/writes touch only this wave's 64 rows -> no barriers inside
    bf16x8 xqf[4][2];
    #pragma unroll
    for (int g = 0; g < 4; g++) {
        xqf[g][0] = *(const bf16x8*)&L.xq[w * 64 + g * 16 + m][quad * 8];
        xqf[g][1] = *(const bf16x8*)&L.xq[w * 64 + g * 16 + m][32 + quad * 8];
    }
    #pragma unroll
    for (int et = 0; et < 4; et++) {
        bf16x8 wf0 = *(const bf16x8*)(wqb + (size_t)(et * 16 + m) * 64 + quad * 8);
        bf16x8 wf1 = *(const bf16x8*)(wqb + (size_t)(et * 16 + m) * 64 + 32 + quad * 8);
        float4 bias = *(const float4*)(bq + et * 16 + quad * 4);
        #pragma unroll
        for (int g = 0; g < 4; g++) {
            f32x4 acc = {0.f, 0.f, 0.f, 0.f};
            acc = MFMA(wf0, xqf[g][0], acc);
            acc = MFMA(wf1, xqf[g][1], acc);
            *(unsigned long long*)&L.xq[w * 64 + g * 16 + m][et * 16 + quad * 4] =
                pack4bf((acc[0] + bias.x) * QSCALE, (acc[1] + bias.y) * QSCALE,
                        (acc[2] + bias.z) * QSCALE, (acc[3] + bias.w) * QSCALE);
        }
    }
    bf16x8 qf[4][2];
    #pragma unroll
    for (int g = 0; g < 4; g++) {
        qf[g][0] = *(const bf16x8*)&L.xq[w * 64 + g * 16 + m][quad * 8];
        qf[g][1] = *(const bf16x8*)&L.xq[w * 64 + g * 16 + m][32 + quad * 8];
    }
    __syncthreads();    // everyone done with xq; union becomes k/v tiles

    float4 bkr[4];
    float  bvr[4];
    #pragma unroll
    for (int et = 0; et < 4; et++) {
        bkr[et] = *(const float4*)(bk + et * 16 + quad * 4);
        bvr[et] = bv[et * 16 + m];
    }

    f32x4 o[4][4];
    float lsum[4] = {0.f, 0.f, 0.f, 0.f};
    #pragma unroll
    for (int g = 0; g < 4; g++)
        #pragma unroll
        for (int n = 0; n < 4; n++) o[g][n] = {0.f, 0.f, 0.f, 0.f};

    const __bf16* xkey = xb + (size_t)bh * 1024 * 64;        // bf16 keys, this bh
    const int p0 = 32 * (w >> 1) + 8 * quad + 4 * (w & 1);   // kappa base, tile t=w

    // prefetch key-x fragments for kb=0 (2 x 16B per lane, direct from global)
    bf16x8 xk0 = *(const bf16x8*)(xkey + (size_t)(w * 16 + m) * 64 + quad * 8);
    bf16x8 xk1 = *(const bf16x8*)(xkey + (size_t)(w * 16 + m) * 64 + 32 + quad * 8);

    for (int kb = 0; kb < 16; kb++) {
        __syncthreads();                 // A: k/v free (prev compute done)

        // issue next kb's key-x loads FIRST (land during proj + compute)
        bf16x8 nx0, nx1;
        if (kb < 15) {
            const __bf16* xrow = xkey + (size_t)((kb + 1) * 64 + w * 16 + m) * 64;
            nx0 = *(const bf16x8*)(xrow + quad * 8);
            nx1 = *(const bf16x8*)(xrow + 32 + quad * 8);
        }

        // ---- proj phase: K/V for this 64-key tile; wave w owns s-tile w ----
        #pragma unroll
        for (int et = 0; et < 4; et++) {
            bf16x8 kw0 = *(const bf16x8*)&lw[0][et * 2 + 0][lane][0];
            bf16x8 kw1 = *(const bf16x8*)&lw[0][et * 2 + 1][lane][0];
            f32x4 ka = {0.f, 0.f, 0.f, 0.f};
            ka = MFMA(kw0, xk0, ka);
            ka = MFMA(kw1, xk1, ka);
            *(unsigned long long*)&L.m.k[w * 16 + m][et * 16 + quad * 4] =
                pack4bf(ka[0] + bkr[et].x, ka[1] + bkr[et].y,
                        ka[2] + bkr[et].z, ka[3] + bkr[et].w);
            bf16x8 vw0 = *(const bf16x8*)&lw[1][et * 2 + 0][lane][0];
            bf16x8 vw1 = *(const bf16x8*)&lw[1][et * 2 + 1][lane][0];
            f32x4 va = {0.f, 0.f, 0.f, 0.f};
            va = MFMA(xk0, vw0, va);
            va = MFMA(xk1, vw1, va);
            *(unsigned long long*)&L.m.v[et * 16 + m][p0] =
                pack4bf(va[0] + bvr[et], va[1] + bvr[et],
                        va[2] + bvr[et], va[3] + bvr[et]);
        }
        __syncthreads();                 // B: k/v tile ready

        // ---- compute phase: QK -> exp2 -> PV ----
        __builtin_amdgcn_s_setprio(1);
        #pragma unroll
        for (int gp = 0; gp < 2; gp++) {
            frag_u pb[2][2];
            #pragma unroll
            for (int t = 0; t < 4; t++) {
                bf16x8 ka0 = *(const bf16x8*)&L.m.k[t * 16 + m][quad * 8];
                bf16x8 ka1 = *(const bf16x8*)&L.m.k[t * 16 + m][32 + quad * 8];
                #pragma unroll
                for (int gl = 0; gl < 2; gl++) {
                    const int g = gp * 2 + gl;
                    f32x4 acc = {0.f, 0.f, 0.f, 0.f};
                    acc = MFMA(ka0, qf[g][0], acc);
                    acc = MFMA(ka1, qf[g][1], acc);
                    float e0 = __builtin_amdgcn_exp2f(acc[0]);
                    float e1 = __builtin_amdgcn_exp2f(acc[1]);
                    float e2 = __builtin_amdgcn_exp2f(acc[2]);
                    float e3 = __builtin_amdgcn_exp2f(acc[3]);
                    lsum[g] += (e0 + e1) + (e2 + e3);
                    pb[gl][t >> 1].u[t & 1] = pack4bf(e0, e1, e2, e3);
                }
            }
            #pragma unroll
            for (int n = 0; n < 4; n++) {
                bf16x8 va0 = *(const bf16x8*)&L.m.v[n * 16 + m][quad * 8];
                bf16x8 va1 = *(const bf16x8*)&L.m.v[n * 16 + m][32 + quad * 8];
                #pragma unroll
                for (int gl = 0; gl < 2; gl++) {
                    const int g = gp * 2 + gl;
                    o[g][n] = MFMA(va0, pb[gl][0].v, o[g][n]);
                    o[g][n] = MFMA(va1, pb[gl][1].v, o[g][n]);
                }
            }
        }
        __builtin_amdgcn_s_setprio(0);

        xk0 = nx0; xk1 = nx1;
    }

    // ---- epilogue: l reduce, O^T regs -> A-fragments, fused @ Wo_perm + bo ----
    #pragma unroll
    for (int g = 0; g < 4; g++) {
        lsum[g] += __shfl_xor(lsum[g], 16);
        lsum[g] += __shfl_xor(lsum[g], 32);
    }

    bf16x8 wf[4][2];
    #pragma unroll
    for (int et = 0; et < 4; et++) {
        wf[et][0] = *(const bf16x8*)(wob + (size_t)(et * 16 + m) * 64 + quad * 8);
        wf[et][1] = *(const bf16x8*)(wob + (size_t)(et * 16 + m) * 64 + 32 + quad * 8);
    }
    float biasr[4];
    #pragma unroll
    for (int et = 0; et < 4; et++) biasr[et] = bo[et * 16 + m];

    #pragma unroll
    for (int g = 0; g < 4; g++) {
        const float inv = 1.f / lsum[g];
        frag_u af0, af1;
        af0.u[0] = pack4bf(o[g][0][0] * inv, o[g][0][1] * inv, o[g][0][2] * inv, o[g][0][3] * inv);
        af0.u[1] = pack4bf(o[g][1][0] * inv, o[g][1][1] * inv, o[g][1][2] * inv, o[g][1][3] * inv);
        af1.u[0] = pack4bf(o[g][2][0] * inv, o[g][2][1] * inv, o[g][2][2] * inv, o[g][2][3] * inv);
        af1.u[1] = pack4bf(o[g][3][0] * inv, o[g][3][1] * inv, o[g][3][2] * inv, o[g][3][3] * inv);
        #pragma unroll
        for (int et = 0; et < 4; et++) {
            f32x4 acc = {0.f, 0.f, 0.f, 0.f};
            acc = MFMA(af0.v, wf[et][0], acc);
            acc = MFMA(af1.v, wf[et][1], acc);
            #pragma unroll
            for (int r = 0; r < 4; r++) {
                size_t row = (size_t)bh * S + q0 + g * 16 + quad * 4 + r;
                out[row * 64 + et * 16 + m] = acc[r] + biasr[et];
            }
        }
    }
}

// ---------------------------------------------------------------------------
extern "C" void kernel_launch(void* const* d_in, const int* in_sizes, int n_in,
                              void* d_out, int out_size, void* d_ws, size_t ws_size,
                              hipStream_t stream) {
    const float* x  = (const float*)d_in[0];
    const float* Wq = (const float*)d_in[1];
    const float* bq = (const float*)d_in[2];
    const float* Wk = (const float*)d_in[3];
    const float* bk = (const float*)d_in[4];
    const float* Wv = (const float*)d_in[5];
    const float* bv = (const float*)d_in[6];
    const float* Wo = (const float*)d_in[7];
    const float* bo = (const float*)d_in[8];
    float* out = (float*)d_out;

    __bf16* xb  = (__bf16*)d_ws;
    __bf16* wob = xb + NE;
    __bf16* wqb = wob + 4096;
    __bf16* wkb = wqb + 4096;
    __bf16* wvb = wkb + 4096;

    prep<<<6160, 256, 0, stream>>>(x, Wq, Wk, Wv, Wo, xb, wqb, wkb, wvb, wob);
    attn<<<dim3(192, 4), 256, 0, stream>>>(xb, wqb, wkb, wvb, wob,
                                           bq, bk, bv, bo, out);
}